// Round 22
// baseline (132.885 us; speedup 1.0000x reference)
//
#include <hip/hip_runtime.h>
#include <hip/hip_bf16.h>

#define BATCH 4
#define SEQ 2048
#define DM 512
#define NH 8
#define DH 64
#define WINDOW 256
#define NEGINF (-1e30f)
#define C_SCALE 0.18033688f   /* 0.125 * 1/ln2 : scores -> log2 domain */
#define THR2 11.5415603f      /* defer-max threshold 8 * 1/ln2 */

typedef __attribute__((ext_vector_type(8)))  short bf16x8;
typedef __attribute__((ext_vector_type(4)))  float f32x4;
typedef __attribute__((ext_vector_type(16))) float f32x16;

__device__ __forceinline__ unsigned short f2bf(float f) {
    __hip_bfloat16 h = __float2bfloat16(f);
    union { __hip_bfloat16 h; unsigned short u; } cv; cv.h = h; return cv.u;
}
__device__ __forceinline__ unsigned int pack2(float a, float b) {
    return (unsigned int)f2bf(a) | ((unsigned int)f2bf(b) << 16);
}

// 64-col bf16 tiles: 128-byte rows, XOR swizzle on byte bits 4-6
__device__ __forceinline__ int swz128(int row, int byte_in_row) {
    return row * 128 + (byte_in_row ^ ((row & 7) << 4));
}

#define MFMA(a, b, c)   __builtin_amdgcn_mfma_f32_16x16x32_bf16(a, b, c, 0, 0, 0)
#define MFMA32(a, b, c) __builtin_amdgcn_mfma_f32_32x32x16_bf16(a, b, c, 0, 0, 0)

// ---------------------------------------------------------------------------
// QKV GEMM (r16-proven): A,W fp32 -> bf16 in staging. 128x128 tile, BK=64,
// 4 waves, double-buffered LDS, one barrier per K-step.
// z == vtz -> V^T output via LDS transpose (coalesced).
// ---------------------------------------------------------------------------
__global__ __launch_bounds__(256, 2) void gemm_qkv(
    const float* __restrict__ A,
    const float* __restrict__ W0f, const float* __restrict__ W1f,
    const float* __restrict__ W2f,
    unsigned short* __restrict__ C0, unsigned short* __restrict__ C1,
    unsigned short* __restrict__ C2, int M, int N, int K, int vtz)
{
    const float* W = (blockIdx.z == 0) ? W0f : (blockIdx.z == 1) ? W1f : W2f;
    unsigned short* C = (blockIdx.z == 0) ? C0 : (blockIdx.z == 1) ? C1 : C2;

    __shared__ unsigned short SMEM[2 * 2 * 128 * 64];   // 64 KB: [buf][A|W]

    const int tid  = threadIdx.x;
    const int m0   = blockIdx.x * 128;
    const int n0   = blockIdx.y * 128;
    const int lane = tid & 63;
    const int wv   = tid >> 6;
    const int wm   = wv >> 1, wn = wv & 1;
    const int g    = lane >> 4;
    const int lr   = lane & 15;
    const int r0   = tid >> 2;
    const int cgrp = tid & 3;
    const int NIT  = K / 64;

    f32x4 acc[4][4];
#pragma unroll
    for (int i = 0; i < 4; ++i)
#pragma unroll
        for (int j = 0; j < 4; ++j) { f32x4 z = {0.f,0.f,0.f,0.f}; acc[i][j] = z; }

    float4 pa[2][4], pwf[2][4];
    auto issue = [&](int it) {
        const int k0 = it * 64;
#pragma unroll
        for (int rr = 0; rr < 2; ++rr) {
            const float* sa = A + (size_t)(m0 + r0 + 64 * rr) * K + k0 + cgrp * 16;
            const float* sw = W + (size_t)(n0 + r0 + 64 * rr) * K + k0 + cgrp * 16;
#pragma unroll
            for (int c = 0; c < 4; ++c) {
                pa[rr][c]  = *reinterpret_cast<const float4*>(sa + 4 * c);
                pwf[rr][c] = *reinterpret_cast<const float4*>(sw + 4 * c);
            }
        }
    };
    auto writeLDS = [&](int buf) {
        unsigned short* As = SMEM + buf * 2 * 128 * 64;
        unsigned short* Ws = As + 128 * 64;
#pragma unroll
        for (int rr = 0; rr < 2; ++rr) {
            const int r = r0 + 64 * rr;
#pragma unroll
            for (int c = 0; c < 4; ++c) {
                const float4 va = pa[rr][c];
                uint2 wa; wa.x = pack2(va.x, va.y); wa.y = pack2(va.z, va.w);
                *reinterpret_cast<uint2*>((char*)As + swz128(r, cgrp * 32 + 8 * c)) = wa;
                const float4 vw = pwf[rr][c];
                uint2 ww; ww.x = pack2(vw.x, vw.y); ww.y = pack2(vw.z, vw.w);
                *reinterpret_cast<uint2*>((char*)Ws + swz128(r, cgrp * 32 + 8 * c)) = ww;
            }
        }
    };

    issue(0);
    writeLDS(0);
    issue(1);

    for (int it = 0; it < NIT; ++it) {
        const int cur = it & 1;
        __syncthreads();
        if (it + 1 < NIT) writeLDS(cur ^ 1);
        if (it + 2 < NIT) issue(it + 2);

        const unsigned short* As = SMEM + cur * 2 * 128 * 64;
        const unsigned short* Ws = As + 128 * 64;
#pragma unroll
        for (int ks = 0; ks < 2; ++ks) {
            bf16x8 af[4], bfr[4];
#pragma unroll
            for (int i = 0; i < 4; ++i)
                af[i] = *reinterpret_cast<const bf16x8*>(
                    (char*)As + swz128(64 * wm + 16 * i + lr, 64 * ks + 16 * g));
#pragma unroll
            for (int j = 0; j < 4; ++j)
                bfr[j] = *reinterpret_cast<const bf16x8*>(
                    (char*)Ws + swz128(64 * wn + 16 * j + lr, 64 * ks + 16 * g));
#pragma unroll
            for (int i = 0; i < 4; ++i)
#pragma unroll
                for (int j = 0; j < 4; ++j)
                    acc[i][j] = MFMA(af[i], bfr[j], acc[i][j]);
        }
    }

    if ((int)blockIdx.z == vtz) {
        // ---- coalesced V^T epilogue: transpose C-tile through LDS ----
        __syncthreads();
        unsigned short* T = SMEM;        // [col 0..127][token 0..127], stride 136
#pragma unroll
        for (int i = 0; i < 4; ++i)
#pragma unroll
            for (int j = 0; j < 4; ++j) {
                const int col  = 64 * wn + 16 * j + lr;
                const int rowb = 64 * wm + 16 * i + 4 * g;
                uint2 v;
                v.x = pack2(acc[i][j][0], acc[i][j][1]);
                v.y = pack2(acc[i][j][2], acc[i][j][3]);
                *reinterpret_cast<uint2*>(&T[col * 136 + rowb]) = v;
            }
        __syncthreads();
        const int col = tid >> 1, hf = tid & 1;
        const int bb  = m0 >> 11;
        unsigned short* dst = C + ((size_t)bb * DM + n0 + col) * SEQ
                                + (m0 & (SEQ - 1)) + 64 * hf;
        const unsigned short* src = &T[col * 136 + 64 * hf];
#pragma unroll
        for (int c = 0; c < 8; ++c)
            *reinterpret_cast<uint4*>(dst + 8 * c) =
                *reinterpret_cast<const uint4*>(src + 8 * c);
        return;
    }

#pragma unroll
    for (int i = 0; i < 4; ++i)
#pragma unroll
        for (int j = 0; j < 4; ++j) {
            const int col = n0 + 64 * wn + 16 * j + lr;
#pragma unroll
            for (int r = 0; r < 4; ++r) {
                const int row = m0 + 64 * wm + 16 * i + 4 * g + r;
                C[(size_t)row * N + col] = f2bf(acc[i][j][r]);
            }
        }
}

// ---------------------------------------------------------------------------
// Output-projection GEMM (r16-proven): A bf16, Wo fp32->bf16 in staging.
// 128x64 tile, BK=64, dbuf LDS, one barrier per K-step.
// ---------------------------------------------------------------------------
__global__ __launch_bounds__(256, 2) void gemm_out(
    const unsigned short* __restrict__ A,
    const float* __restrict__ Wf,
    float* __restrict__ C, int M, int N, int K)
{
    __shared__ unsigned short SMEM[2 * (128 * 64 + 64 * 64)];   // 48 KB

    const int tid  = threadIdx.x;
    const int m0   = blockIdx.x * 128;
    const int n0   = blockIdx.y * 64;
    const int lane = tid & 63;
    const int wv   = tid >> 6;
    const int g    = lane >> 4;
    const int lr   = lane & 15;
    const int r0   = tid >> 2;
    const int cgrp = tid & 3;
    const int NIT  = K / 64;

    f32x4 acc[2][4];
#pragma unroll
    for (int i = 0; i < 2; ++i)
#pragma unroll
        for (int j = 0; j < 4; ++j) { f32x4 z = {0.f,0.f,0.f,0.f}; acc[i][j] = z; }

    uint4  pa[2][2];
    float4 pwf[4];
    auto issue = [&](int it) {
        const int k0 = it * 64;
#pragma unroll
        for (int rr = 0; rr < 2; ++rr) {
            const unsigned short* sa =
                A + (size_t)(m0 + r0 + 64 * rr) * K + k0 + cgrp * 16;
            pa[rr][0] = *reinterpret_cast<const uint4*>(sa);
            pa[rr][1] = *reinterpret_cast<const uint4*>(sa + 8);
        }
        const float* sw = Wf + (size_t)(n0 + r0) * K + k0 + cgrp * 16;
#pragma unroll
        for (int c = 0; c < 4; ++c)
            pwf[c] = *reinterpret_cast<const float4*>(sw + 4 * c);
    };
    auto writeLDS = [&](int buf) {
        unsigned short* As = SMEM + buf * (128 * 64 + 64 * 64);
        unsigned short* Ws = As + 128 * 64;
#pragma unroll
        for (int rr = 0; rr < 2; ++rr) {
            const int r = r0 + 64 * rr;
            *reinterpret_cast<uint4*>((char*)As + swz128(r, cgrp * 32))      = pa[rr][0];
            *reinterpret_cast<uint4*>((char*)As + swz128(r, cgrp * 32 + 16)) = pa[rr][1];
        }
#pragma unroll
        for (int c = 0; c < 4; ++c) {
            const float4 vw = pwf[c];
            uint2 ww; ww.x = pack2(vw.x, vw.y); ww.y = pack2(vw.z, vw.w);
            *reinterpret_cast<uint2*>((char*)Ws + swz128(r0, cgrp * 32 + 8 * c)) = ww;
        }
    };

    issue(0);
    writeLDS(0);
    issue(1);

    for (int it = 0; it < NIT; ++it) {
        const int cur = it & 1;
        __syncthreads();
        if (it + 1 < NIT) writeLDS(cur ^ 1);
        if (it + 2 < NIT) issue(it + 2);

        const unsigned short* As = SMEM + cur * (128 * 64 + 64 * 64);
        const unsigned short* Ws = As + 128 * 64;
#pragma unroll
        for (int ks = 0; ks < 2; ++ks) {
            bf16x8 af[2], bfr[4];
#pragma unroll
            for (int i = 0; i < 2; ++i)
                af[i] = *reinterpret_cast<const bf16x8*>(
                    (char*)As + swz128(32 * wv + 16 * i + lr, 64 * ks + 16 * g));
#pragma unroll
            for (int j = 0; j < 4; ++j)
                bfr[j] = *reinterpret_cast<const bf16x8*>(
                    (char*)Ws + swz128(16 * j + lr, 64 * ks + 16 * g));
#pragma unroll
            for (int i = 0; i < 2; ++i)
#pragma unroll
                for (int j = 0; j < 4; ++j)
                    acc[i][j] = MFMA(af[i], bfr[j], acc[i][j]);
        }
    }

#pragma unroll
    for (int i = 0; i < 2; ++i)
#pragma unroll
        for (int j = 0; j < 4; ++j) {
            const int col = n0 + 16 * j + lr;
#pragma unroll
            for (int r = 0; r < 4; ++r) {
                const int row = m0 + 32 * wv + 16 * i + 4 * g + r;
                C[(size_t)row * N + col] = acc[i][j][r];
            }
        }
}

// ---------------------------------------------------------------------------
// Flash attention, kv-split occupancy variant. Block = 4 waves over 64 q:
// wave w -> (qhalf = w>>1: q 0-31/32-63, kvhalf = w&1: kv 0-31/32-63 of each
// staged 64-kv tile). Each wave keeps its own online-softmax partial (o,m,l);
// exact merge of the two kvhalf partials in LDS at the end. Grid 1024 blocks
// (4/CU resident: VGPR ~100, 32KB dynamic LDS) -> 16 waves/CU vs 8.
// Staging/double-buffer/prefetch/setprio identical to the verified body.
// ---------------------------------------------------------------------------
__global__ __launch_bounds__(256) void attn_split64(
    const unsigned short* __restrict__ Q, const unsigned short* __restrict__ K,
    const unsigned short* __restrict__ VtG, const int* __restrict__ amask,
    unsigned short* __restrict__ AO)
{
    extern __shared__ unsigned short SMEM[];   // 32 KB: Ks0,Ks1,Vt0,Vt1 (8KB ea)

    const int tid = threadIdx.x;
    const int x   = (int)blockIdx.x;                    // 0..1023
    const int r_  = (x < 512) ? x : 1535 - x;           // balanced rank
    const int qb  = 31 - (r_ >> 5);                     // qb desc by rank
    const int bh  = r_ & 31;
    const int n0  = qb * 64;
    const int b = bh >> 3, h = bh & 7;

    const int lane = tid & 63;
    const int wv   = tid >> 6;
    const int qh   = wv >> 1;       // q half (0: rows 0-31, 1: rows 32-63)
    const int kh   = wv & 1;        // kv half of each 64-kv tile
    const int ql   = lane & 31;
    const int hb   = lane >> 5;

    const int qrow  = n0 + 32 * qh + ql;
    const int qminw = n0 + 32 * qh;
    const int qmaxw = qminw + 31;

    bf16x8 qf[4];
    {
        const unsigned short* qp =
            Q + (size_t)(b * SEQ + qrow) * DM + h * DH + 8 * hb;
#pragma unroll
        for (int st = 0; st < 4; ++st)
            qf[st] = *reinterpret_cast<const bf16x8*>(qp + 16 * st);
    }

    f32x16 o[2];
#pragma unroll
    for (int i = 0; i < 16; ++i) { o[0][i] = 0.f; o[1][i] = 0.f; }
    float m_run = NEGINF, l_run = 0.f;

    int ntiles = (n0 + 63 + WINDOW - 1) / 64 + 1;
    if (ntiles > SEQ / 64) ntiles = SEQ / 64;

    const int r_st = tid & 63;           // K staging row
    const int half = tid >> 6;           // K staging 32B chunk
    const int vd   = tid >> 2;           // V staging d-row 0..63
    const int vc   = (tid & 3) * 8;      // V staging kv chunk (8 kv = 16B)
    const unsigned short* kpt = K + (size_t)(b * SEQ + r_st) * DM + h * DH + 16 * half;
    const unsigned short* vpt = VtG + ((size_t)b * DM + h * DH + vd) * SEQ + vc;
    const int* amp = amask + (size_t)b * SEQ + r_st;

    uint4 kr0, kr1, vv0, vv1; int mr = 1;
    auto issue = [&](int tt) {
        const unsigned short* kp = kpt + (size_t)tt * 64 * DM;
        kr0 = *reinterpret_cast<const uint4*>(kp);
        kr1 = *reinterpret_cast<const uint4*>(kp + 8);
        const unsigned short* vp = vpt + tt * 64;
        vv0 = *reinterpret_cast<const uint4*>(vp);
        vv1 = *reinterpret_cast<const uint4*>(vp + 32);
        mr = amp[tt * 64];
    };
    auto writeKV = [&](int buf) {
        unsigned short* KsB = SMEM + buf * 4096;
        unsigned short* VtB = SMEM + 8192 + buf * 4096;
        *reinterpret_cast<uint4*>((char*)KsB + swz128(r_st, 32 * half))      = kr0;
        *reinterpret_cast<uint4*>((char*)KsB + swz128(r_st, 32 * half + 16)) = kr1;
        *reinterpret_cast<uint4*>((char*)VtB + swz128(vd, 2 * vc))           = vv0;
        *reinterpret_cast<uint4*>((char*)VtB + swz128(vd, 2 * vc + 64))      = vv1;
    };

    unsigned long long mw0 = ~0ULL, mw1 = ~0ULL;

    issue(0);
    writeKV(0);
    mw0 = __ballot(mr != 0);
    issue(1);

    for (int t = 0; t < ntiles; ++t) {
        const int cur = t & 1;
        __syncthreads();   // buf[cur] (tile t) visible; buf[cur^1] readers done
        if (t + 1 < ntiles) {
            writeKV(cur ^ 1);
            const unsigned long long bw = __ballot(mr != 0);
            if (cur == 0) mw1 = bw; else mw0 = bw;
        }
        if (t + 2 < ntiles) issue(t + 2);

        const int kv0s = t * 64 + 32 * kh;           // this wave's sub-tile base
        if (kv0s > qmaxw + (WINDOW - 1)) continue;   // wave fully below band

        const unsigned long long mwt = cur ? mw1 : mw0;
        const bool fullband =
            ((kv0s + 31 - qminw) <= (WINDOW - 1)) && (mwt == ~0ULL);
        const unsigned short* KsB = SMEM + cur * 4096;
        const unsigned short* VtB = SMEM + 8192 + cur * 4096;

        // ---- S = K Q^T : one 32x32 acc tile (this wave's kv half) ----
        f32x16 s;
#pragma unroll
        for (int i = 0; i < 16; ++i) s[i] = 0.f;
        __builtin_amdgcn_s_setprio(1);
#pragma unroll
        for (int st = 0; st < 4; ++st) {
            bf16x8 kf = *reinterpret_cast<const bf16x8*>(
                (char*)KsB + swz128(32 * kh + ql, 32 * st + 16 * hb));
            s = MFMA32(kf, qf[st], s);
        }
        __builtin_amdgcn_s_setprio(0);

        // ---- mask (boundary tiles only); kvi = 32kh + (rg&3)+8(rg>>2)+4hb ----
        if (!fullband) {
            const int lim = qrow + (WINDOW - 1) - t * 64;
#pragma unroll
            for (int rg = 0; rg < 16; ++rg) {
                const int kvi = 32 * kh + (rg & 3) + 8 * (rg >> 2) + 4 * hb;
                const bool ok = (kvi <= lim) && ((mwt >> kvi) & 1ULL);
                s[rg] = ok ? s[rg] : NEGINF;
            }
        }

        // ---- lane-local row max (16 values) + cross-half reduce ----
        float tmax = NEGINF;
#pragma unroll
        for (int rg = 0; rg < 16; ++rg) tmax = fmaxf(tmax, s[rg]);
        tmax = fmaxf(tmax, __shfl_xor(tmax, 32));
        const float tm2 = tmax * C_SCALE;

        // ---- defer-max rescale (scalar per lane, no shuffles) ----
        if (!__all(tm2 - m_run <= THR2)) {
            const float mn = fmaxf(m_run, tm2);
            const float sc = exp2f(m_run - mn);
            m_run = mn; l_run *= sc;
#pragma unroll
            for (int rg = 0; rg < 16; ++rg) { o[0][rg] *= sc; o[1][rg] *= sc; }
        }

        // ---- P = exp2(s*C - m); pack pairs with v_cvt_pk_bf16_f32 ----
        float ls = 0.f;
        unsigned int pw8[8];
#pragma unroll
        for (int i = 0; i < 8; ++i) {
            const float p0 = exp2f(fmaf(s[2 * i],     C_SCALE, -m_run));
            const float p1 = exp2f(fmaf(s[2 * i + 1], C_SCALE, -m_run));
            ls += p0 + p1;
            unsigned int r;
            asm("v_cvt_pk_bf16_f32 %0, %1, %2" : "=v"(r) : "v"(p0), "v"(p1));
            pw8[i] = r;
        }
        ls += __shfl_xor(ls, 32);
        l_run += ls;

        // ---- O^T += V^T P over this wave's 32 kv (2 k-slots) ----
        __builtin_amdgcn_s_setprio(1);
#pragma unroll
        for (int c = 0; c < 2; ++c) {
            const int base = 4 * c;
            unsigned int a0 = pw8[base],     b0 = pw8[base + 2];
            unsigned int a1 = pw8[base + 1], b1 = pw8[base + 3];
            asm("v_permlane32_swap_b32 %0, %1" : "+v"(a0), "+v"(b0));
            asm("v_permlane32_swap_b32 %0, %1" : "+v"(a1), "+v"(b1));
            union { unsigned int w[4]; bf16x8 v; } pf;
            pf.w[0] = a0; pf.w[1] = a1; pf.w[2] = b0; pf.w[3] = b1;
#pragma unroll
            for (int dt = 0; dt < 2; ++dt) {
                bf16x8 vf = *reinterpret_cast<const bf16x8*>(
                    (char*)VtB + swz128(32 * dt + ql, 64 * kh + 32 * c + 16 * hb));
                o[dt] = MFMA32(vf, pf.v, o[dt]);
            }
        }
        __builtin_amdgcn_s_setprio(0);
    }

    // ---- exact merge of kvhalf partials via LDS (reuse K/V buffers) ----
    __syncthreads();   // all compute done before overwriting LDS
    float* MRG = (float*)SMEM;
    float* slot = MRG + ((size_t)qh * 64 + lane) * 34;
    if (kh == 1) {
#pragma unroll
        for (int i = 0; i < 16; ++i) { slot[i] = o[0][i]; slot[16 + i] = o[1][i]; }
        slot[32] = m_run; slot[33] = l_run;
    }
    __syncthreads();
    if (kh == 0) {
        const float m1 = slot[32], l1 = slot[33];
        const float M  = fmaxf(m_run, m1);
        const float w0 = exp2f(m_run - M);
        const float w1 = exp2f(m1 - M);
        const float inv = 1.f / (l_run * w0 + l1 * w1);
        unsigned short* op = AO + (size_t)(b * SEQ + qrow) * DM + h * DH;
#pragma unroll
        for (int dt = 0; dt < 2; ++dt)
#pragma unroll
            for (int p = 0; p < 4; ++p) {
                const float f0 = (o[dt][4 * p]     * w0 + slot[16 * dt + 4 * p]     * w1) * inv;
                const float f1 = (o[dt][4 * p + 1] * w0 + slot[16 * dt + 4 * p + 1] * w1) * inv;
                const float f2 = (o[dt][4 * p + 2] * w0 + slot[16 * dt + 4 * p + 2] * w1) * inv;
                const float f3 = (o[dt][4 * p + 3] * w0 + slot[16 * dt + 4 * p + 3] * w1) * inv;
                unsigned int w0p, w1p;
                asm("v_cvt_pk_bf16_f32 %0, %1, %2" : "=v"(w0p) : "v"(f0), "v"(f1));
                asm("v_cvt_pk_bf16_f32 %0, %1, %2" : "=v"(w1p) : "v"(f2), "v"(f3));
                uint2 st; st.x = w0p; st.y = w1p;
                *reinterpret_cast<uint2*>(op + 32 * dt + 8 * p + 4 * hb) = st;
            }
    }
}

extern "C" void kernel_launch(void* const* d_in, const int* in_sizes, int n_in,
                              void* d_out, int out_size, void* d_ws, size_t ws_size,
                              hipStream_t stream) {
    const float* hs    = (const float*)d_in[0];
    const int*   amask = (const int*)  d_in[1];
    const float* Wq    = (const float*)d_in[2];
    const float* Wk    = (const float*)d_in[3];
    const float* Wv    = (const float*)d_in[4];
    const float* Wo    = (const float*)d_in[5];
    float* out = (float*)d_out;

    const size_t tok = (size_t)BATCH * SEQ * DM;
    unsigned short* Qb  = (unsigned short*)d_ws;
    unsigned short* Kb  = Qb + tok;
    unsigned short* VtG = Kb + tok;     // V^T: [b][dm][s]
    unsigned short* AOb = VtG + tok;

    const int M = BATCH * SEQ;

    dim3 gQKV(M / 128, DM / 128, 3);
    gemm_qkv<<<gQKV, 256, 0, stream>>>(hs, Wq, Wk, Wv, Qb, Kb, VtG, M, DM, DM, 2);

    attn_split64<<<dim3(1024), 256, 32768, stream>>>(Qb, Kb, VtG, amask, AOb);

    dim3 gOut(M / 128, DM / 64);
    gemm_out<<<gOut, 256, 0, stream>>>(AOb, Wo, out, M, DM, DM);
}

// Round 23
// 115.954 us; speedup vs baseline: 1.1460x; 1.1460x over previous
//
#include <hip/hip_runtime.h>
#include <hip/hip_bf16.h>

#define BATCH 4
#define SEQ 2048
#define DM 512
#define NH 8
#define DH 64
#define WINDOW 256
#define NEGINF (-1e30f)
#define C_SCALE 0.18033688f   /* 0.125 * 1/ln2 : scores -> log2 domain */
#define THR2 11.5415603f      /* defer-max threshold 8 * 1/ln2 */

typedef __attribute__((ext_vector_type(8)))  short bf16x8;
typedef __attribute__((ext_vector_type(4)))  float f32x4;
typedef __attribute__((ext_vector_type(16))) float f32x16;

__device__ __forceinline__ unsigned short f2bf(float f) {
    __hip_bfloat16 h = __float2bfloat16(f);
    union { __hip_bfloat16 h; unsigned short u; } cv; cv.h = h; return cv.u;
}
__device__ __forceinline__ unsigned int pack2(float a, float b) {
    return (unsigned int)f2bf(a) | ((unsigned int)f2bf(b) << 16);
}

// 64-col bf16 tiles: 128-byte rows, XOR swizzle on byte bits 4-6
__device__ __forceinline__ int swz128(int row, int byte_in_row) {
    return row * 128 + (byte_in_row ^ ((row & 7) << 4));
}

#define MFMA(a, b, c)   __builtin_amdgcn_mfma_f32_16x16x32_bf16(a, b, c, 0, 0, 0)
#define MFMA32(a, b, c) __builtin_amdgcn_mfma_f32_32x32x16_bf16(a, b, c, 0, 0, 0)

// ---------------------------------------------------------------------------
// QKV GEMM (r16-proven): A,W fp32 -> bf16 in staging. 128x128 tile, BK=64,
// 4 waves, double-buffered LDS, one barrier per K-step.
// z == vtz -> V^T output via LDS transpose (coalesced).
// ---------------------------------------------------------------------------
__global__ __launch_bounds__(256, 2) void gemm_qkv(
    const float* __restrict__ A,
    const float* __restrict__ W0f, const float* __restrict__ W1f,
    const float* __restrict__ W2f,
    unsigned short* __restrict__ C0, unsigned short* __restrict__ C1,
    unsigned short* __restrict__ C2, int M, int N, int K, int vtz)
{
    const float* W = (blockIdx.z == 0) ? W0f : (blockIdx.z == 1) ? W1f : W2f;
    unsigned short* C = (blockIdx.z == 0) ? C0 : (blockIdx.z == 1) ? C1 : C2;

    __shared__ unsigned short SMEM[2 * 2 * 128 * 64];   // 64 KB: [buf][A|W]

    const int tid  = threadIdx.x;
    const int m0   = blockIdx.x * 128;
    const int n0   = blockIdx.y * 128;
    const int lane = tid & 63;
    const int wv   = tid >> 6;
    const int wm   = wv >> 1, wn = wv & 1;
    const int g    = lane >> 4;
    const int lr   = lane & 15;
    const int r0   = tid >> 2;
    const int cgrp = tid & 3;
    const int NIT  = K / 64;

    f32x4 acc[4][4];
#pragma unroll
    for (int i = 0; i < 4; ++i)
#pragma unroll
        for (int j = 0; j < 4; ++j) { f32x4 z = {0.f,0.f,0.f,0.f}; acc[i][j] = z; }

    float4 pa[2][4], pwf[2][4];
    auto issue = [&](int it) {
        const int k0 = it * 64;
#pragma unroll
        for (int rr = 0; rr < 2; ++rr) {
            const float* sa = A + (size_t)(m0 + r0 + 64 * rr) * K + k0 + cgrp * 16;
            const float* sw = W + (size_t)(n0 + r0 + 64 * rr) * K + k0 + cgrp * 16;
#pragma unroll
            for (int c = 0; c < 4; ++c) {
                pa[rr][c]  = *reinterpret_cast<const float4*>(sa + 4 * c);
                pwf[rr][c] = *reinterpret_cast<const float4*>(sw + 4 * c);
            }
        }
    };
    auto writeLDS = [&](int buf) {
        unsigned short* As = SMEM + buf * 2 * 128 * 64;
        unsigned short* Ws = As + 128 * 64;
#pragma unroll
        for (int rr = 0; rr < 2; ++rr) {
            const int r = r0 + 64 * rr;
#pragma unroll
            for (int c = 0; c < 4; ++c) {
                const float4 va = pa[rr][c];
                uint2 wa; wa.x = pack2(va.x, va.y); wa.y = pack2(va.z, va.w);
                *reinterpret_cast<uint2*>((char*)As + swz128(r, cgrp * 32 + 8 * c)) = wa;
                const float4 vw = pwf[rr][c];
                uint2 ww; ww.x = pack2(vw.x, vw.y); ww.y = pack2(vw.z, vw.w);
                *reinterpret_cast<uint2*>((char*)Ws + swz128(r, cgrp * 32 + 8 * c)) = ww;
            }
        }
    };

    issue(0);
    writeLDS(0);
    issue(1);

    for (int it = 0; it < NIT; ++it) {
        const int cur = it & 1;
        __syncthreads();
        if (it + 1 < NIT) writeLDS(cur ^ 1);
        if (it + 2 < NIT) issue(it + 2);

        const unsigned short* As = SMEM + cur * 2 * 128 * 64;
        const unsigned short* Ws = As + 128 * 64;
#pragma unroll
        for (int ks = 0; ks < 2; ++ks) {
            bf16x8 af[4], bfr[4];
#pragma unroll
            for (int i = 0; i < 4; ++i)
                af[i] = *reinterpret_cast<const bf16x8*>(
                    (char*)As + swz128(64 * wm + 16 * i + lr, 64 * ks + 16 * g));
#pragma unroll
            for (int j = 0; j < 4; ++j)
                bfr[j] = *reinterpret_cast<const bf16x8*>(
                    (char*)Ws + swz128(64 * wn + 16 * j + lr, 64 * ks + 16 * g));
#pragma unroll
            for (int i = 0; i < 4; ++i)
#pragma unroll
                for (int j = 0; j < 4; ++j)
                    acc[i][j] = MFMA(af[i], bfr[j], acc[i][j]);
        }
    }

    if ((int)blockIdx.z == vtz) {
        // ---- coalesced V^T epilogue: transpose C-tile through LDS ----
        __syncthreads();
        unsigned short* T = SMEM;        // [col 0..127][token 0..127], stride 136
#pragma unroll
        for (int i = 0; i < 4; ++i)
#pragma unroll
            for (int j = 0; j < 4; ++j) {
                const int col  = 64 * wn + 16 * j + lr;
                const int rowb = 64 * wm + 16 * i + 4 * g;
                uint2 v;
                v.x = pack2(acc[i][j][0], acc[i][j][1]);
                v.y = pack2(acc[i][j][2], acc[i][j][3]);
                *reinterpret_cast<uint2*>(&T[col * 136 + rowb]) = v;
            }
        __syncthreads();
        const int col = tid >> 1, hf = tid & 1;
        const int bb  = m0 >> 11;
        unsigned short* dst = C + ((size_t)bb * DM + n0 + col) * SEQ
                                + (m0 & (SEQ - 1)) + 64 * hf;
        const unsigned short* src = &T[col * 136 + 64 * hf];
#pragma unroll
        for (int c = 0; c < 8; ++c)
            *reinterpret_cast<uint4*>(dst + 8 * c) =
                *reinterpret_cast<const uint4*>(src + 8 * c);
        return;
    }

#pragma unroll
    for (int i = 0; i < 4; ++i)
#pragma unroll
        for (int j = 0; j < 4; ++j) {
            const int col = n0 + 64 * wn + 16 * j + lr;
#pragma unroll
            for (int r = 0; r < 4; ++r) {
                const int row = m0 + 64 * wm + 16 * i + 4 * g + r;
                C[(size_t)row * N + col] = f2bf(acc[i][j][r]);
            }
        }
}

// ---------------------------------------------------------------------------
// Output-projection GEMM (r16-proven): A bf16, Wo fp32->bf16 in staging.
// 128x64 tile, BK=64, dbuf LDS, one barrier per K-step.
// ---------------------------------------------------------------------------
__global__ __launch_bounds__(256, 2) void gemm_out(
    const unsigned short* __restrict__ A,
    const float* __restrict__ Wf,
    float* __restrict__ C, int M, int N, int K)
{
    __shared__ unsigned short SMEM[2 * (128 * 64 + 64 * 64)];   // 48 KB

    const int tid  = threadIdx.x;
    const int m0   = blockIdx.x * 128;
    const int n0   = blockIdx.y * 64;
    const int lane = tid & 63;
    const int wv   = tid >> 6;
    const int g    = lane >> 4;
    const int lr   = lane & 15;
    const int r0   = tid >> 2;
    const int cgrp = tid & 3;
    const int NIT  = K / 64;

    f32x4 acc[2][4];
#pragma unroll
    for (int i = 0; i < 2; ++i)
#pragma unroll
        for (int j = 0; j < 4; ++j) { f32x4 z = {0.f,0.f,0.f,0.f}; acc[i][j] = z; }

    uint4  pa[2][2];
    float4 pwf[4];
    auto issue = [&](int it) {
        const int k0 = it * 64;
#pragma unroll
        for (int rr = 0; rr < 2; ++rr) {
            const unsigned short* sa =
                A + (size_t)(m0 + r0 + 64 * rr) * K + k0 + cgrp * 16;
            pa[rr][0] = *reinterpret_cast<const uint4*>(sa);
            pa[rr][1] = *reinterpret_cast<const uint4*>(sa + 8);
        }
        const float* sw = Wf + (size_t)(n0 + r0) * K + k0 + cgrp * 16;
#pragma unroll
        for (int c = 0; c < 4; ++c)
            pwf[c] = *reinterpret_cast<const float4*>(sw + 4 * c);
    };
    auto writeLDS = [&](int buf) {
        unsigned short* As = SMEM + buf * (128 * 64 + 64 * 64);
        unsigned short* Ws = As + 128 * 64;
#pragma unroll
        for (int rr = 0; rr < 2; ++rr) {
            const int r = r0 + 64 * rr;
            *reinterpret_cast<uint4*>((char*)As + swz128(r, cgrp * 32))      = pa[rr][0];
            *reinterpret_cast<uint4*>((char*)As + swz128(r, cgrp * 32 + 16)) = pa[rr][1];
        }
#pragma unroll
        for (int c = 0; c < 4; ++c) {
            const float4 vw = pwf[c];
            uint2 ww; ww.x = pack2(vw.x, vw.y); ww.y = pack2(vw.z, vw.w);
            *reinterpret_cast<uint2*>((char*)Ws + swz128(r0, cgrp * 32 + 8 * c)) = ww;
        }
    };

    issue(0);
    writeLDS(0);
    issue(1);

    for (int it = 0; it < NIT; ++it) {
        const int cur = it & 1;
        __syncthreads();
        if (it + 1 < NIT) writeLDS(cur ^ 1);
        if (it + 2 < NIT) issue(it + 2);

        const unsigned short* As = SMEM + cur * (128 * 64 + 64 * 64);
        const unsigned short* Ws = As + 128 * 64;
#pragma unroll
        for (int ks = 0; ks < 2; ++ks) {
            bf16x8 af[2], bfr[4];
#pragma unroll
            for (int i = 0; i < 2; ++i)
                af[i] = *reinterpret_cast<const bf16x8*>(
                    (char*)As + swz128(32 * wv + 16 * i + lr, 64 * ks + 16 * g));
#pragma unroll
            for (int j = 0; j < 4; ++j)
                bfr[j] = *reinterpret_cast<const bf16x8*>(
                    (char*)Ws + swz128(16 * j + lr, 64 * ks + 16 * g));
#pragma unroll
            for (int i = 0; i < 2; ++i)
#pragma unroll
                for (int j = 0; j < 4; ++j)
                    acc[i][j] = MFMA(af[i], bfr[j], acc[i][j]);
        }
    }

#pragma unroll
    for (int i = 0; i < 2; ++i)
#pragma unroll
        for (int j = 0; j < 4; ++j) {
            const int col = n0 + 16 * j + lr;
#pragma unroll
            for (int r = 0; r < 4; ++r) {
                const int row = m0 + 32 * wv + 16 * i + 4 * g + r;
                C[(size_t)row * N + col] = acc[i][j][r];
            }
        }
}

// ---------------------------------------------------------------------------
// Flash attention (r16-proven, 59.5us @ VGPR 124 / 32KB LDS — do not grow
// either): 32x32x16 bf16 MFMA, swapped operands. Block = 4 waves x 32 q.
// Double-buffered K/V LDS, ONE barrier per tile; full-iteration register
// prefetch; setprio around MFMA clusters; work-balanced grid mapping.
// Probed-and-rejected variants: KVBLK=128 (LDS cliff, r17), tree reductions
// (+16 VGPR, r18), 64x128 GEMM tiles (reuse loss, r20), kv-split (staging/
// barrier doubling, r22), 2-wave blocks (r11/r12), global-direct (r7).
// ---------------------------------------------------------------------------
__global__ __launch_bounds__(256) void attn_mfma32(
    const unsigned short* __restrict__ Q, const unsigned short* __restrict__ K,
    const unsigned short* __restrict__ VtG, const int* __restrict__ amask,
    unsigned short* __restrict__ AO)
{
    __shared__ unsigned short Ks[2][64 * 64];   // [kv][d] swizzled
    __shared__ unsigned short Vt[2][64 * 64];   // [d][kv] swizzled

    const int tid = threadIdx.x;
    const int x   = (int)blockIdx.x;                    // 0..511
    const int r_  = (x < 256) ? x : 767 - x;            // rank, big/small half
    const int qb  = 15 - (r_ >> 5);                     // qb desc by rank
    const int bh  = r_ & 31;
    const int n0  = qb * 128;
    const int b = bh >> 3, h = bh & 7;

    const int lane = tid & 63;
    const int wv   = tid >> 6;
    const int ql   = lane & 31;
    const int hb   = lane >> 5;

    const int qrow  = n0 + 32 * wv + ql;
    const int qminw = n0 + 32 * wv;
    const int qmaxw = qminw + 31;

    bf16x8 qf[4];
    {
        const unsigned short* qp =
            Q + (size_t)(b * SEQ + qrow) * DM + h * DH + 8 * hb;
#pragma unroll
        for (int st = 0; st < 4; ++st)
            qf[st] = *reinterpret_cast<const bf16x8*>(qp + 16 * st);
    }

    f32x16 o[2];
#pragma unroll
    for (int i = 0; i < 16; ++i) { o[0][i] = 0.f; o[1][i] = 0.f; }
    float m_run = NEGINF, l_run = 0.f;

    int ntiles = (n0 + 127 + WINDOW - 1) / 64 + 1;
    if (ntiles > SEQ / 64) ntiles = SEQ / 64;

    const int r_st = tid & 63;           // K staging row
    const int half = tid >> 6;           // K staging 32B chunk
    const int vd   = tid >> 2;           // V staging d-row 0..63
    const int vc   = (tid & 3) * 8;      // V staging kv chunk (8 kv = 16B)
    const unsigned short* kpt = K + (size_t)(b * SEQ + r_st) * DM + h * DH + 16 * half;
    const unsigned short* vpt = VtG + ((size_t)b * DM + h * DH + vd) * SEQ + vc;
    const int* amp = amask + (size_t)b * SEQ + r_st;

    uint4 kr0, kr1, vv0, vv1; int mr = 1;
    auto issue = [&](int tt) {
        const unsigned short* kp = kpt + (size_t)tt * 64 * DM;
        kr0 = *reinterpret_cast<const uint4*>(kp);
        kr1 = *reinterpret_cast<const uint4*>(kp + 8);
        const unsigned short* vp = vpt + tt * 64;
        vv0 = *reinterpret_cast<const uint4*>(vp);
        vv1 = *reinterpret_cast<const uint4*>(vp + 32);
        mr = amp[tt * 64];
    };
    auto writeKV = [&](int buf) {
        *reinterpret_cast<uint4*>((char*)Ks[buf] + swz128(r_st, 32 * half))      = kr0;
        *reinterpret_cast<uint4*>((char*)Ks[buf] + swz128(r_st, 32 * half + 16)) = kr1;
        *reinterpret_cast<uint4*>((char*)Vt[buf] + swz128(vd, 2 * vc))           = vv0;
        *reinterpret_cast<uint4*>((char*)Vt[buf] + swz128(vd, 2 * vc + 64))      = vv1;
    };

    unsigned long long mw0 = ~0ULL, mw1 = ~0ULL;

    issue(0);
    writeKV(0);
    mw0 = __ballot(mr != 0);
    issue(1);

    for (int t = 0; t < ntiles; ++t) {
        const int cur = t & 1;
        const int kv0 = t * 64;
        __syncthreads();   // buf[cur] (tile t) visible; buf[cur^1] readers done
        if (t + 1 < ntiles) {
            writeKV(cur ^ 1);
            const unsigned long long bw = __ballot(mr != 0);
            if (cur == 0) mw1 = bw; else mw0 = bw;
        }
        if (t + 2 < ntiles) issue(t + 2);

        if (kv0 > qmaxw + (WINDOW - 1)) continue;   // wave fully below band

        const unsigned long long mwt = cur ? mw1 : mw0;
        const bool fullband =
            ((kv0 + 63 - qminw) <= (WINDOW - 1)) && (mwt == ~0ULL);

        // ---- S = K Q^T : 2 acc tiles (kv 0-31, 32-63) ----
        f32x16 s[2];
        __builtin_amdgcn_s_setprio(1);
#pragma unroll
        for (int T = 0; T < 2; ++T) {
            f32x16 z;
#pragma unroll
            for (int i = 0; i < 16; ++i) z[i] = 0.f;
#pragma unroll
            for (int st = 0; st < 4; ++st) {
                bf16x8 kf = *reinterpret_cast<const bf16x8*>(
                    (char*)Ks[cur] + swz128(32 * T + ql, 32 * st + 16 * hb));
                z = MFMA32(kf, qf[st], z);
            }
            s[T] = z;
        }
        __builtin_amdgcn_s_setprio(0);

        // ---- mask (boundary tiles only); kv = 32T + (rg&3)+8(rg>>2)+4hb ----
        if (!fullband) {
            const int lim = qrow + (WINDOW - 1) - kv0;
#pragma unroll
            for (int T = 0; T < 2; ++T)
#pragma unroll
                for (int rg = 0; rg < 16; ++rg) {
                    const int kvi = 32 * T + (rg & 3) + 8 * (rg >> 2) + 4 * hb;
                    const bool ok = (kvi <= lim) && ((mwt >> kvi) & 1ULL);
                    s[T][rg] = ok ? s[T][rg] : NEGINF;
                }
        }

        // ---- lane-local row max (32 values) + cross-half reduce ----
        float tmax = NEGINF;
#pragma unroll
        for (int T = 0; T < 2; ++T)
#pragma unroll
            for (int rg = 0; rg < 16; ++rg) tmax = fmaxf(tmax, s[T][rg]);
        tmax = fmaxf(tmax, __shfl_xor(tmax, 32));
        const float tm2 = tmax * C_SCALE;

        // ---- defer-max rescale (scalar per lane, no shuffles) ----
        if (!__all(tm2 - m_run <= THR2)) {
            const float mn = fmaxf(m_run, tm2);
            const float sc = exp2f(m_run - mn);
            m_run = mn; l_run *= sc;
#pragma unroll
            for (int rg = 0; rg < 16; ++rg) { o[0][rg] *= sc; o[1][rg] *= sc; }
        }

        // ---- P = exp2(s*C - m); pack pairs with v_cvt_pk_bf16_f32 ----
        float ls = 0.f;
        unsigned int pw[16];
#pragma unroll
        for (int T = 0; T < 2; ++T)
#pragma unroll
            for (int i = 0; i < 8; ++i) {
                const float p0 = exp2f(fmaf(s[T][2 * i],     C_SCALE, -m_run));
                const float p1 = exp2f(fmaf(s[T][2 * i + 1], C_SCALE, -m_run));
                ls += p0 + p1;
                unsigned int r;
                asm("v_cvt_pk_bf16_f32 %0, %1, %2" : "=v"(r) : "v"(p0), "v"(p1));
                pw[8 * T + i] = r;
            }
        ls += __shfl_xor(ls, 32);
        l_run += ls;

        // ---- O^T += V^T P : B-frag via one permlane32_swap per word pair ----
        __builtin_amdgcn_s_setprio(1);
#pragma unroll
        for (int c = 0; c < 4; ++c) {
            const int base = 8 * (c >> 1) + 4 * (c & 1);
            unsigned int a0 = pw[base],     b0 = pw[base + 2];
            unsigned int a1 = pw[base + 1], b1 = pw[base + 3];
            asm("v_permlane32_swap_b32 %0, %1" : "+v"(a0), "+v"(b0));
            asm("v_permlane32_swap_b32 %0, %1" : "+v"(a1), "+v"(b1));
            union { unsigned int w[4]; bf16x8 v; } pf;
            pf.w[0] = a0; pf.w[1] = a1; pf.w[2] = b0; pf.w[3] = b1;
#pragma unroll
            for (int dt = 0; dt < 2; ++dt) {
                bf16x8 vf = *reinterpret_cast<const bf16x8*>(
                    (char*)Vt[cur] + swz128(32 * dt + ql, 32 * c + 16 * hb));
                o[dt] = MFMA32(vf, pf.v, o[dt]);
            }
        }
        __builtin_amdgcn_s_setprio(0);
    }

    // ---- normalize + store O^T: lane q=qrow, d = (rg&3)+8(rg>>2)+4hb+32dt ----
    const float inv = 1.f / l_run;
    unsigned short* op = AO + (size_t)(b * SEQ + qrow) * DM + h * DH;
#pragma unroll
    for (int dt = 0; dt < 2; ++dt)
#pragma unroll
        for (int p = 0; p < 4; ++p) {
            const float f0 = o[dt][4 * p]     * inv, f1 = o[dt][4 * p + 1] * inv;
            const float f2 = o[dt][4 * p + 2] * inv, f3 = o[dt][4 * p + 3] * inv;
            unsigned int w0, w1;
            asm("v_cvt_pk_bf16_f32 %0, %1, %2" : "=v"(w0) : "v"(f0), "v"(f1));
            asm("v_cvt_pk_bf16_f32 %0, %1, %2" : "=v"(w1) : "v"(f2), "v"(f3));
            uint2 st; st.x = w0; st.y = w1;
            *reinterpret_cast<uint2*>(op + 32 * dt + 8 * p + 4 * hb) = st;
        }
}

extern "C" void kernel_launch(void* const* d_in, const int* in_sizes, int n_in,
                              void* d_out, int out_size, void* d_ws, size_t ws_size,
                              hipStream_t stream) {
    const float* hs    = (const float*)d_in[0];
    const int*   amask = (const int*)  d_in[1];
    const float* Wq    = (const float*)d_in[2];
    const float* Wk    = (const float*)d_in[3];
    const float* Wv    = (const float*)d_in[4];
    const float* Wo    = (const float*)d_in[5];
    float* out = (float*)d_out;

    const size_t tok = (size_t)BATCH * SEQ * DM;
    unsigned short* Qb  = (unsigned short*)d_ws;
    unsigned short* Kb  = Qb + tok;
    unsigned short* VtG = Kb + tok;     // V^T: [b][dm][s]
    unsigned short* AOb = VtG + tok;

    const int M = BATCH * SEQ;

    dim3 gQKV(M / 128, DM / 128, 3);
    gemm_qkv<<<gQKV, 256, 0, stream>>>(hs, Wq, Wk, Wv, Qb, Kb, VtG, M, DM, DM, 2);

    attn_mfma32<<<dim3(512), 256, 0, stream>>>(Qb, Kb, VtG, amask, AOb);

    dim3 gOut(M / 128, DM / 64);
    gemm_out<<<gOut, 256, 0, stream>>>(AOb, Wo, out, M, DM, DM);
}